// Round 6
// baseline (254.657 us; speedup 1.0000x reference)
//
#include <hip/hip_runtime.h>
#include <math.h>

// CRF negative log-likelihood. Round 6: INSTRUMENTATION round.
// R5 kernel body executed twice per block (opaque rep offset defeats CSE),
// each rep adds 0.5*local -> result identical, kernel duration ~2x so the
// crf_kernel dispatch clears the 78-us fill kernels and gets a counter row.

#define B_TOT 16384
#define M_LEN 16
#define D_DIM 128
#define L_LAB 26
#define WPB 4
#define NBLOCKS (B_TOT / (WPB * 2))   // 2048 blocks, 2 batches per wave
#define LOG2E 1.4426950408889634f
#define LN2   0.6931471805599453f
#define DELTA 5.7f
#define ESTR 36                        // Ee row stride in floats

typedef short v8s __attribute__((ext_vector_type(8)));   // 8 bf16
typedef float v4f __attribute__((ext_vector_type(4)));   // 4 fp32 acc

static __device__ __forceinline__ unsigned bf16u(float f) {
    unsigned u = __float_as_uint(f);
    u += 0x7fff + ((u >> 16) & 1);     // RNE
    return u >> 16;
}
static __device__ __forceinline__ unsigned pkbf(float lo, float hi) {
    return bf16u(lo) | (bf16u(hi) << 16);
}
static __device__ __forceinline__ float fexp2(float x) {
#if __has_builtin(__builtin_amdgcn_exp2f)
    return __builtin_amdgcn_exp2f(x);
#else
    return exp2f(x);
#endif
}
static __device__ __forceinline__ float flog2(float x) {
#if __has_builtin(__builtin_amdgcn_logf)
    return __builtin_amdgcn_logf(x);
#else
    return log2f(x);
#endif
}

__global__ void prep_kernel(const float* __restrict__ W, const float* __restrict__ T,
                            uint4* __restrict__ wsW, float* __restrict__ wsP) {
    const int l = threadIdx.x;       // 64 threads
    const int c16 = l & 15, quad = l >> 4;
    #pragma unroll
    for (int f = 0; f < 8; ++f) {
        const int tile = f >> 2, kk = f & 3;
        const int label = tile * 16 + c16;
        const int base = kk * 32 + quad * 8;
        unsigned d[4];
        #pragma unroll
        for (int p = 0; p < 4; ++p) {
            float a = 0.f, bb = 0.f;
            if (label < L_LAB) {
                a  = W[label * D_DIM + base + 2 * p]     * LOG2E;
                bb = W[label * D_DIM + base + 2 * p + 1] * LOG2E;
            }
            d[p] = pkbf(a, bb);
        }
        wsW[l * 8 + f] = make_uint4(d[0], d[1], d[2], d[3]);
    }
    for (int i = l; i < 1024; i += 64) {
        const int j = i >> 5, k = i & 31;
        wsP[i] = (j < L_LAB && k < L_LAB)
               ? exp2f(T[k * L_LAB + j] * LOG2E - DELTA) : 0.f;
    }
}

__global__ __launch_bounds__(256, 4) void crf_kernel(
    const float* __restrict__ X, const int* __restrict__ Y,
    const float* __restrict__ T, const uint4* __restrict__ wsW,
    const float* __restrict__ wsP, float* __restrict__ out,
    int rep_off)                       // runtime 0: defeats rep-CSE
{
    const int lane = threadIdx.x & 63;
    const int wave = threadIdx.x >> 6;
    const int g = lane >> 5;             // batch half
    const int j = lane & 31;             // label (valid < 26)
    const int c16 = lane & 15;           // MFMA col / row-group
    const int quad = lane >> 4;

    __shared__ float Ts[L_LAB * L_LAB];
    __shared__ float Ee[WPB][2][M_LEN * ESTR];
    __shared__ float vrow[WPB][2][32];
    __shared__ float red[WPB];

    for (int i = threadIdx.x; i < L_LAB * L_LAB; i += 256) Ts[i] = T[i];

    uint4 wf[8];
    #pragma unroll
    for (int f = 0; f < 8; ++f) wf[f] = wsW[lane * 8 + f];

    __syncthreads();   // Ts ready

    const int wgid = blockIdx.x * WPB + wave;

    for (int rep = 0; rep < 2; ++rep) {
        const float* Xr = X + (size_t)rep * (size_t)rep_off;
        const int*   Yr = Y + (size_t)rep * (size_t)rep_off;
        __syncthreads();   // red[] from previous rep consumed

        // ---- emissions via MFMA, 2 batches, epilogue applies exp2 ----
        #pragma unroll
        for (int g2 = 0; g2 < 2; ++g2) {
            const float* xb = Xr + (size_t)(wgid * 2 + g2) * (M_LEN * D_DIM);
            v4f acc0 = {0.f, 0.f, 0.f, 0.f};
            v4f acc1 = {0.f, 0.f, 0.f, 0.f};
            #pragma unroll
            for (int kk = 0; kk < 4; ++kk) {
                const float4* xp = (const float4*)(xb + c16 * D_DIM + kk * 32 + quad * 8);
                float4 xa = xp[0];
                float4 xc = xp[1];
                uint4 au = make_uint4(pkbf(xa.x, xa.y), pkbf(xa.z, xa.w),
                                      pkbf(xc.x, xc.y), pkbf(xc.z, xc.w));
                v8s af = *(v8s*)&au;
                v8s b0 = *(v8s*)&wf[kk];
                v8s b1 = *(v8s*)&wf[4 + kk];
                acc0 = __builtin_amdgcn_mfma_f32_16x16x32_bf16(af, b0, acc0, 0, 0, 0);
                acc1 = __builtin_amdgcn_mfma_f32_16x16x32_bf16(af, b1, acc1, 0, 0, 0);
            }
            #pragma unroll
            for (int r = 0; r < 4; ++r) {
                const int s = quad * 4 + r;
                Ee[wave][g2][s * ESTR + c16]      = fexp2(acc0[r]);
                Ee[wave][g2][s * ESTR + 16 + c16] = fexp2(acc1[r]);
            }
        }

        // ---- P' columns ----
        float4 Pc4[7];
        {
            const float4* pp = (const float4*)(wsP + j * 32);
            #pragma unroll
            for (int t = 0; t < 7; ++t) Pc4[t] = pp[t];
        }
        // ---- preload per-step E_s[j] ----
        float Ejs[15];
        #pragma unroll
        for (int s = 1; s < M_LEN; ++s) Ejs[s - 1] = Ee[wave][g][s * ESTR + j];

        // ---- node + edge potentials ----
        float ne = 0.f;
        if (j < M_LEN) {
            const int bb = wgid * 2 + g;
            const int ys = Yr[bb * M_LEN + j];
            ne = flog2(Ee[wave][g][j * ESTR + ys]) * LN2;
            if (j < M_LEN - 1) {
                const int yn = Yr[bb * M_LEN + j + 1];
                ne += Ts[ys * L_LAB + yn];
            }
        }
        ne += __shfl_xor(ne, 8);
        ne += __shfl_xor(ne, 4);
        ne += __shfl_xor(ne, 2);
        ne += __shfl_xor(ne, 1);

        // ---- recurrence ----
        float4 v4[7];
        {
            const float4* e0 = (const float4*)&Ee[wave][g][0];
            #pragma unroll
            for (int t = 0; t < 7; ++t) v4[t] = e0[t];
        }
        #pragma unroll
        for (int s = 1; s < M_LEN; ++s) {
            float4 u4 = make_float4(0.f, 0.f, 0.f, 0.f);
            #pragma unroll
            for (int t = 0; t < 7; ++t) {
                u4.x = fmaf(v4[t].x, Pc4[t].x, u4.x);
                u4.y = fmaf(v4[t].y, Pc4[t].y, u4.y);
                u4.z = fmaf(v4[t].z, Pc4[t].z, u4.z);
                u4.w = fmaf(v4[t].w, Pc4[t].w, u4.w);
            }
            const float u = (u4.x + u4.z) + (u4.y + u4.w);
            vrow[wave][g][j] = u * Ejs[s - 1];
            const float4* vr = (const float4*)&vrow[wave][g][0];
            #pragma unroll
            for (int t = 0; t < 7; ++t) v4[t] = vr[t];
        }

        // ---- log partition ----
        float4 sv = make_float4(0.f, 0.f, 0.f, 0.f);
        #pragma unroll
        for (int t = 0; t < 7; ++t) {
            sv.x += v4[t].x; sv.y += v4[t].y; sv.z += v4[t].z; sv.w += v4[t].w;
        }
        const float logz = (flog2((sv.x + sv.z) + (sv.y + sv.w)) + 15.f * DELTA) * LN2;

        float local = logz - ne;
        const float other = __shfl(local, 32);
        if (lane == 0) red[wave] = local + other;
        __syncthreads();
        if (threadIdx.x == 0) {
            atomicAdd(out, 0.5f * ((red[0] + red[1]) + (red[2] + red[3])));
        }
    }
}

extern "C" void kernel_launch(void* const* d_in, const int* in_sizes, int n_in,
                              void* d_out, int out_size, void* d_ws, size_t ws_size,
                              hipStream_t stream) {
    const float* X = (const float*)d_in[0];
    const int*   Y = (const int*)d_in[1];
    const float* W = (const float*)d_in[2];
    const float* T = (const float*)d_in[3];
    float* out = (float*)d_out;
    uint4* wsW = (uint4*)d_ws;                         // 8 KB
    float* wsP = (float*)((char*)d_ws + 8192);         // 4 KB

    hipMemsetAsync(out, 0, sizeof(float), stream);
    prep_kernel<<<1, 64, 0, stream>>>(W, T, wsW, wsP);
    crf_kernel<<<NBLOCKS, 256, 0, stream>>>(X, Y, T, wsW, wsP, out, 0);
}

// Round 7
// 225.308 us; speedup vs baseline: 1.1303x; 1.1303x over previous
//
#include <hip/hip_runtime.h>
#include <math.h>

// CRF negative log-likelihood. Round 7: DPP-systolic recurrence (zero LDS in loop).
// B=16384, M=16, D=128, L=26. 2 batches per wave, lane = 2k + g
//   (k = label slot 0..31, g = batch parity).
//
// v_s[k] = 2^{alpha_s[k] + e2[s][k] - s*delta};  v_0 = E_0;
// v_s = (v_{s-1} . P') * E_s.  Matvec done as a 32-step systolic ring:
// rotate v by one k-step (= 2 lanes, wave_ror:1 twice; parity-preserving so
// both batches share the ring) and fmac against ring-ordered P' coefficients
// wsPr[lane][t] precomputed by prep_kernel WITH THE SAME DPP SEQUENCE
// (direction-agnostic by construction). No ds ops, no shuffles in the loop.

#define B_TOT 16384
#define M_LEN 16
#define D_DIM 128
#define L_LAB 26
#define WPB 4
#define NBLOCKS (B_TOT / (WPB * 2))   // 2048 blocks, 2 batches per wave
#define LOG2E 1.4426950408889634f
#define LN2   0.6931471805599453f
#define DELTA 5.7f
#define ESTR 36                        // Ee row stride in floats

typedef short v8s __attribute__((ext_vector_type(8)));   // 8 bf16
typedef float v4f __attribute__((ext_vector_type(4)));   // 4 fp32 acc

static __device__ __forceinline__ unsigned bf16u(float f) {
    unsigned u = __float_as_uint(f);
    u += 0x7fff + ((u >> 16) & 1);     // RNE
    return u >> 16;
}
static __device__ __forceinline__ unsigned pkbf(float lo, float hi) {
    return bf16u(lo) | (bf16u(hi) << 16);
}
static __device__ __forceinline__ float fexp2(float x) {
#if __has_builtin(__builtin_amdgcn_exp2f)
    return __builtin_amdgcn_exp2f(x);
#else
    return exp2f(x);
#endif
}
static __device__ __forceinline__ float flog2(float x) {
#if __has_builtin(__builtin_amdgcn_logf)
    return __builtin_amdgcn_logf(x);
#else
    return log2f(x);
#endif
}

// rotate whole wave right by 2 lanes = advance label-ring by 1 (parity kept)
static __device__ __forceinline__ int ror2i(int x) {
    x = __builtin_amdgcn_update_dpp(0, x, 0x13C, 0xF, 0xF, true);  // wave_ror:1
    x = __builtin_amdgcn_update_dpp(0, x, 0x13C, 0xF, 0xF, true);
    return x;
}
static __device__ __forceinline__ float ror2f(float x) {
    return __int_as_float(ror2i(__float_as_int(x)));
}

// Precompute (a) W MFMA B-fragments (bf16, *log2e, labels zero-padded to 32);
// (b) ring-ordered P' table wsPr[l*32+t] = P'[rk_l(t)][k_l], rk chain via the
//     SAME ror2 the main kernel uses. P'[a][b] = 2^{T[a][b]*log2e - delta}.
__global__ void prep_kernel(const float* __restrict__ W, const float* __restrict__ T,
                            uint4* __restrict__ wsW, float* __restrict__ wsPr) {
    const int l = threadIdx.x;       // 64 threads = 1 wave (DPP-safe)
    const int c16 = l & 15, quad = l >> 4;
    #pragma unroll
    for (int f = 0; f < 8; ++f) {
        const int tile = f >> 2, kk = f & 3;
        const int label = tile * 16 + c16;
        const int base = kk * 32 + quad * 8;
        unsigned d[4];
        #pragma unroll
        for (int p = 0; p < 4; ++p) {
            float a = 0.f, bb = 0.f;
            if (label < L_LAB) {
                a  = W[label * D_DIM + base + 2 * p]     * LOG2E;
                bb = W[label * D_DIM + base + 2 * p + 1] * LOG2E;
            }
            d[p] = pkbf(a, bb);
        }
        wsW[l * 8 + f] = make_uint4(d[0], d[1], d[2], d[3]);
    }
    const int k = l >> 1;
    int rk = k;
    for (int t = 0; t < 32; ++t) {       // uniform trip count: DPP-safe
        wsPr[l * 32 + t] = (rk < L_LAB && k < L_LAB)
            ? exp2f(T[rk * L_LAB + k] * LOG2E - DELTA) : 0.f;
        rk = ror2i(rk);
    }
}

__global__ __launch_bounds__(256, 4) void crf_kernel(
    const float* __restrict__ X, const int* __restrict__ Y,
    const float* __restrict__ T, const uint4* __restrict__ wsW,
    const float* __restrict__ wsPr, float* __restrict__ out)
{
    const int lane = threadIdx.x & 63;
    const int wave = threadIdx.x >> 6;
    const int k = lane >> 1;             // label slot 0..31 (valid < 26)
    const int g = lane & 1;              // batch parity
    const int c16 = lane & 15;           // MFMA col / row-group
    const int quad = lane >> 4;

    __shared__ float Ts[L_LAB * L_LAB];            // natural units (edge)
    __shared__ float Ee[WPB][2][M_LEN * ESTR];     // E = 2^{e2}
    __shared__ float red[WPB];

    for (int i = threadIdx.x; i < L_LAB * L_LAB; i += 256) Ts[i] = T[i];

    uint4 wf[8];
    #pragma unroll
    for (int f = 0; f < 8; ++f) wf[f] = wsW[lane * 8 + f];

    __syncthreads();   // Ts ready

    const int wgid = blockIdx.x * WPB + wave;

    // ---- emissions via MFMA, 2 batches, epilogue applies exp2 ----
    #pragma unroll
    for (int g2 = 0; g2 < 2; ++g2) {
        const float* xb = X + (size_t)(wgid * 2 + g2) * (M_LEN * D_DIM);
        v4f acc0 = {0.f, 0.f, 0.f, 0.f};
        v4f acc1 = {0.f, 0.f, 0.f, 0.f};
        #pragma unroll
        for (int kk = 0; kk < 4; ++kk) {
            const float4* xp = (const float4*)(xb + c16 * D_DIM + kk * 32 + quad * 8);
            float4 xa = xp[0];
            float4 xc = xp[1];
            uint4 au = make_uint4(pkbf(xa.x, xa.y), pkbf(xa.z, xa.w),
                                  pkbf(xc.x, xc.y), pkbf(xc.z, xc.w));
            v8s af = *(v8s*)&au;
            v8s b0 = *(v8s*)&wf[kk];
            v8s b1 = *(v8s*)&wf[4 + kk];
            acc0 = __builtin_amdgcn_mfma_f32_16x16x32_bf16(af, b0, acc0, 0, 0, 0);
            acc1 = __builtin_amdgcn_mfma_f32_16x16x32_bf16(af, b1, acc1, 0, 0, 0);
        }
        // C layout: col = lane&15 (label), row s = quad*4 + r (position)
        #pragma unroll
        for (int r = 0; r < 4; ++r) {
            const int s = quad * 4 + r;
            Ee[wave][g2][s * ESTR + c16]      = fexp2(acc0[r]);
            Ee[wave][g2][s * ESTR + 16 + c16] = fexp2(acc1[r]);  // pads: e2=0 -> E=1
        }
    }
    // Ee written & read by the same wave only: DS pipe in-order, no barrier.

    // ---- ring-ordered P' coefficients: 8x dwordx4, L2-resident table ----
    float Pr[32];
    {
        const float4* pp = (const float4*)(wsPr + lane * 32);
        #pragma unroll
        for (int t8 = 0; t8 < 8; ++t8) {
            float4 q = pp[t8];
            Pr[4 * t8 + 0] = q.x; Pr[4 * t8 + 1] = q.y;
            Pr[4 * t8 + 2] = q.z; Pr[4 * t8 + 3] = q.w;
        }
    }

    // ---- preload per-step E_s[k] and v-init (lane 2k+g: batch g, label k) ----
    float Ejs[15];
    #pragma unroll
    for (int s = 1; s < M_LEN; ++s) Ejs[s - 1] = Ee[wave][g][s * ESTR + k];
    float v = Ee[wave][g][k];            // v_0 = E_0 (pads = 1, zeroed after step 1)

    // ---- node + edge potentials ----
    float ne = 0.f;
    if (lane < 32) {                     // lane = 2s+g, s = 0..15
        const int s = lane >> 1;
        const int b = wgid * 2 + g;
        const int ys = Y[b * M_LEN + s];
        ne = flog2(Ee[wave][g][s * ESTR + ys]) * LN2;
        if (s < M_LEN - 1) {
            const int yn = Y[b * M_LEN + s + 1];
            ne += Ts[ys * L_LAB + yn];
        }
    }
    ne += __shfl_xor(ne, 32);
    ne += __shfl_xor(ne, 16);
    ne += __shfl_xor(ne, 8);
    ne += __shfl_xor(ne, 4);
    ne += __shfl_xor(ne, 2);             // parity-preserving: per-batch sum in all lanes

    // ---- recurrence: 15 x 32-step systolic ring, pure VALU ----
    #pragma unroll
    for (int s = 1; s < M_LEN; ++s) {
        float vr = v;
        float u0 = 0.f, u1 = 0.f;
        #pragma unroll
        for (int t = 0; t < 32; t += 2) {
            u0 = fmaf(vr, Pr[t], u0);
            vr = ror2f(vr);
            u1 = fmaf(vr, Pr[t + 1], u1);
            if (t < 30) vr = ror2f(vr);
        }
        v = (u0 + u1) * Ejs[s - 1];      // pads: P' cols zero -> v stays 0
    }

    // ---- log partition: sum v over same-parity lanes ----
    float tot = v;
    tot += __shfl_xor(tot, 32);
    tot += __shfl_xor(tot, 16);
    tot += __shfl_xor(tot, 8);
    tot += __shfl_xor(tot, 4);
    tot += __shfl_xor(tot, 2);
    const float logz = (flog2(tot) + 15.f * DELTA) * LN2;

    float local = logz - ne;                       // per-parity value
    const float pair = local + __shfl_xor(local, 1);  // b0 + b1
    if (lane == 0) red[wave] = pair;
    __syncthreads();
    if (threadIdx.x == 0) atomicAdd(out, (red[0] + red[1]) + (red[2] + red[3]));
}

extern "C" void kernel_launch(void* const* d_in, const int* in_sizes, int n_in,
                              void* d_out, int out_size, void* d_ws, size_t ws_size,
                              hipStream_t stream) {
    const float* X = (const float*)d_in[0];
    const int*   Y = (const int*)d_in[1];
    const float* W = (const float*)d_in[2];
    const float* T = (const float*)d_in[3];
    float* out = (float*)d_out;
    uint4* wsW  = (uint4*)d_ws;                        // 8 KB
    float* wsPr = (float*)((char*)d_ws + 8192);        // 8 KB ring table

    hipMemsetAsync(out, 0, sizeof(float), stream);
    prep_kernel<<<1, 64, 0, stream>>>(W, T, wsW, wsPr);
    crf_kernel<<<NBLOCKS, 256, 0, stream>>>(X, Y, T, wsW, wsPr, out);
}